// Round 4
// baseline (510.386 us; speedup 1.0000x reference)
//
#include <hip/hip_runtime.h>
#include <hip/hip_bf16.h>

#define E_EDGES 320000
#define N_NODES 10000

typedef __attribute__((ext_vector_type(8))) short short8;
typedef __attribute__((ext_vector_type(4))) float floatx4;

__device__ __forceinline__ float bf2f(unsigned short u) {
    union { unsigned int i; float f; } v; v.i = ((unsigned int)u) << 16; return v.f;
}
// pack two fp32 -> bf16x2 (RNE), low = a
__device__ __forceinline__ unsigned int pk2(float a, float b) {
    float2 t; t.x = a; t.y = b;
    __hip_bfloat162 h = __float22bfloat162_rn(t);
    union { __hip_bfloat162 h; unsigned int u; } c; c.h = h; return c.u;
}

// ---- A-fragment batch load (weights, fragment-tiled in global), kt0 = K-tile base.
// Caller wraps with __builtin_amdgcn_sched_barrier(0) to pin issue position.
template<int KT, int FT>
__device__ __forceinline__ void load_a(const unsigned short* __restrict__ wt, int ntiles, int t0,
                                       int kt0, int lane, short8 (&a)[KT][FT])
{
#pragma unroll
    for (int kt = 0; kt < KT; ++kt)
#pragma unroll
        for (int ft = 0; ft < FT; ++ft)
            a[kt][ft] = *(const short8*)&wt[(size_t)((kt0 + kt) * ntiles + t0 + ft) * 512 + lane * 8];
}

// ---- MFMA layer, SWAPPED operands: A = weights (registers), B = acts (LDS).
// acc[ft][et]: D col=lane&15 -> edge (et*16+mrow), row=quad*4+r -> feature (n0+ft*16+quad*4+r).
// ZERO=false accumulates into acc (split-K).
template<int K, int FT, int ET, bool ZERO>
__device__ __forceinline__ void layer_mfma(const unsigned short* __restrict__ in, int istride,
                                           int lane, const short8 (&a)[K / 32][FT],
                                           floatx4 (&acc)[FT][ET])
{
    constexpr int KT = K / 32;
    const int quad = lane >> 4;
    const int mrow = lane & 15;
    if (ZERO) {
        floatx4 zero = {0.f, 0.f, 0.f, 0.f};
#pragma unroll
        for (int ft = 0; ft < FT; ++ft)
#pragma unroll
            for (int et = 0; et < ET; ++et)
                acc[ft][et] = zero;
    }
#pragma unroll
    for (int kt = 0; kt < KT; ++kt) {
        const int koff = kt * 32 + quad * 8;
        short8 b[ET];
#pragma unroll
        for (int et = 0; et < ET; ++et)
            b[et] = *(const short8*)&in[(et * 16 + mrow) * istride + koff];
#pragma unroll
        for (int ft = 0; ft < FT; ++ft)
#pragma unroll
            for (int et = 0; et < ET; ++et)
                acc[ft][et] = __builtin_amdgcn_mfma_f32_16x16x32_bf16(a[kt][ft], b[et], acc[ft][et], 0, 0, 0);
    }
}

// layer_stream: A (global) and B (LDS) double-buffered depth-1 — for K=416 (A too big for regs).
template<int K, int Nn, int ET>
__device__ __forceinline__ void layer_stream(const unsigned short* __restrict__ in, int istride,
                                             const unsigned short* __restrict__ wt,
                                             int lane, int n0, floatx4 (&acc)[2][ET])
{
    constexpr int KT = K / 32;
    const int quad = lane >> 4;
    const int mrow = lane & 15;

    floatx4 zero = {0.f, 0.f, 0.f, 0.f};
#pragma unroll
    for (int ft = 0; ft < 2; ++ft)
#pragma unroll
        for (int et = 0; et < ET; ++et)
            acc[ft][et] = zero;

    short8 a[2][2];
    short8 b[2][ET];
#pragma unroll
    for (int ft = 0; ft < 2; ++ft)
        a[0][ft] = *(const short8*)&wt[(size_t)((n0 >> 4) + ft) * 512 + lane * 8];
#pragma unroll
    for (int et = 0; et < ET; ++et)
        b[0][et] = *(const short8*)&in[(et * 16 + mrow) * istride + quad * 8];

#pragma unroll
    for (int kt = 0; kt < KT; ++kt) {
        if (kt + 1 < KT) {
            const int nb = (kt + 1) & 1;
            const int koff = (kt + 1) * 32 + quad * 8;
#pragma unroll
            for (int ft = 0; ft < 2; ++ft)
                a[nb][ft] = *(const short8*)&wt[(size_t)((kt + 1) * (Nn >> 4) + (n0 >> 4) + ft) * 512 + lane * 8];
#pragma unroll
            for (int et = 0; et < ET; ++et)
                b[nb][et] = *(const short8*)&in[(et * 16 + mrow) * istride + koff];
        }
#pragma unroll
        for (int ft = 0; ft < 2; ++ft)
#pragma unroll
            for (int et = 0; et < ET; ++et)
                acc[ft][et] = __builtin_amdgcn_mfma_f32_16x16x32_bf16(a[kt & 1][ft], b[kt & 1][et], acc[ft][et], 0, 0, 0);
    }
}

// store D to LDS [edge][feature] bf16: 4 consecutive features per reg-quad -> one ds_write_b64
template<int FT, int ET>
__device__ __forceinline__ void store_lds(floatx4 (&acc)[FT][ET], const float* __restrict__ bias,
                                          int lane, int n0, unsigned short* __restrict__ out, int ostride,
                                          bool relu)
{
    const int quad = lane >> 4, mrow = lane & 15;
#pragma unroll
    for (int ft = 0; ft < FT; ++ft) {
        int fbase = n0 + ft * 16 + quad * 4;
        float4 bv = *(const float4*)&bias[fbase];
#pragma unroll
        for (int et = 0; et < ET; ++et) {
            int edge = et * 16 + mrow;
            float v0 = acc[ft][et][0] + bv.x;
            float v1 = acc[ft][et][1] + bv.y;
            float v2 = acc[ft][et][2] + bv.z;
            float v3 = acc[ft][et][3] + bv.w;
            if (relu) {
                v0 = v0 > 0.f ? v0 : 0.f; v1 = v1 > 0.f ? v1 : 0.f;
                v2 = v2 > 0.f ? v2 : 0.f; v3 = v3 > 0.f ? v3 : 0.f;
            }
            uint2 pk; pk.x = pk2(v0, v1); pk.y = pk2(v2, v3);
            *(uint2*)&out[edge * ostride + fbase] = pk;
        }
    }
}

// ---------------- fused prep: weight repack + degree histogram + s-zeroing ----------------
struct TDesc { const float* src; unsigned short* dst; int nElem; int logN; int blockStart; };
struct TArgs { TDesc d[8]; };

__global__ void prep_kernel(TArgs a, const int* __restrict__ eidx, int* __restrict__ cnt,
                            float4* __restrict__ s4, int histStart, int zeroStart)
{
    int b = blockIdx.x;
    if (b >= zeroStart) {
        // zero s: 2500 blocks x 256 threads x float4 = N_NODES*256 floats exact
        int idx = (b - zeroStart) * 256 + threadIdx.x;
        float4 z = {0.f, 0.f, 0.f, 0.f};
        s4[idx] = z;
        return;
    }
    if (b >= histStart) {
        int e = (b - histStart) * 256 + threadIdx.x;
        if (e < E_EDGES) atomicAdd(&cnt[eidx[E_EDGES + e]], 1);
        return;
    }
    int i = 0;
#pragma unroll
    for (int j = 1; j < 8; ++j)
        if (b >= a.d[j].blockStart) i = j;
    const TDesc t = a.d[i];
    int idx = (b - t.blockStart) * 256 + threadIdx.x;
    if (idx < t.nElem) {
        int n = idx & ((1 << t.logN) - 1);
        int k = idx >> t.logN;
        int ntiles = 1 << (t.logN - 4);
        size_t dsti = ((size_t)(k >> 5) * ntiles + (n >> 4)) * 512
                    + ((k >> 3) & 3) * 128 + (n & 15) * 8 + (k & 7);
        union { float f; unsigned int u; } c; c.f = t.src[idx];
        unsigned int uu = c.u;
        t.dst[dsti] = (unsigned short)((uu + 0x7fffu + ((uu >> 16) & 1u)) >> 16);
    }
}

__global__ void scan_kernel(const int* __restrict__ cnt, int* __restrict__ fill)
{
    __shared__ int partial[256];
    const int CH = 40;                      // 256*40 = 10240 >= N_NODES
    int tid = threadIdx.x;
    int base = tid * CH;
    int local[CH];
    int sum = 0;
#pragma unroll
    for (int j = 0; j < CH; ++j) {
        int idx = base + j;
        int c = (idx < N_NODES) ? cnt[idx] : 0;
        local[j] = c;
        sum += c;
    }
    partial[tid] = sum;
    __syncthreads();
    for (int o = 1; o < 256; o <<= 1) {
        int v = (tid >= o) ? partial[tid - o] : 0;
        __syncthreads();
        partial[tid] += v;
        __syncthreads();
    }
    int run = partial[tid] - sum;
#pragma unroll
    for (int j = 0; j < CH; ++j) {
        int idx = base + j;
        if (idx < N_NODES) fill[idx] = run;
        run += local[j];
    }
}

// pack (edge, src, dst) into ONE int4 store: 1 random cacheline per edge instead of 3
__global__ void fill_kernel(const int* __restrict__ eidx, int* __restrict__ fill,
                            int4* __restrict__ pack)
{
    int e = blockIdx.x * 256 + threadIdx.x;
    int c = eidx[E_EDGES + e];
    int r = eidx[e];
    int pos = atomicAdd(&fill[c], 1);
    pack[pos] = make_int4(e, r, c, 0);
}

// ---------------- edge MLP: 64 edges/block, split-K L0 + split-feature L3 ----------------
// LDS: region A @0 [64][136] (H0half / H2 / G-pass), region B @17408 [64][136] (H1 / H3).
// Total 34816 B + 768 idx -> 4 blocks/CU.
__global__ __launch_bounds__(256, 4) void edge_kernel(
    const float* __restrict__ x,
    const float* __restrict__ ea,
    const int4* __restrict__ pack,
    const unsigned short* __restrict__ wt0, const float* __restrict__ b0,
    const unsigned short* __restrict__ wt1, const float* __restrict__ b1,
    const unsigned short* __restrict__ wt2, const float* __restrict__ b2,
    const unsigned short* __restrict__ wt3, const float* __restrict__ b3,
    float* __restrict__ s)
{
    __shared__ __align__(16) char U[34816];
    __shared__ int es[64];
    __shared__ int rs[64];
    __shared__ int ds[64];

    unsigned short* A = (unsigned short*)U;            // H0half, H2, G
    unsigned short* B = (unsigned short*)(U + 17408);  // H1, H3

    const int tid = threadIdx.x;
    const int p0 = blockIdx.x * 64;

    if (tid < 64) {
        int4 pr = pack[p0 + tid];
        es[tid] = pr.x; rs[tid] = pr.y; ds[tid] = pr.z;
    }
    __syncthreads();

    const int lane = tid & 63;
    const int wave = tid >> 6;
    const int t32 = wave * 2;   // feature-tile base (32 features/wave, L0-L2)
    const int quad = lane >> 4, mrow = lane & 15;

    // ---- Phase S: batch-issue x loads + ea loads + L0 first-half A-frags; write x-part.
    float4 vx[8], ve[8];
#pragma unroll
    for (int i = 0; i < 8; ++i) {                  // 64 rows x 32 parts
        int task = tid + i * 256;
        int row = task >> 5, part = task & 31;
        vx[i] = *(const float4*)(x + (size_t)rs[row] * 128 + part * 4);
    }
#pragma unroll
    for (int i = 0; i < 8; ++i) {
        int task = tid + i * 256;
        int row = task >> 5, part = task & 31;
        ve[i] = *(const float4*)(ea + (size_t)es[row] * 128 + part * 4);
    }
    __builtin_amdgcn_sched_barrier(0);
    short8 a0a[4][2];
    load_a<4, 2>(wt0, 8, t32, 0, lane, a0a);       // L0 weights kt 0..3 (x half)
    __builtin_amdgcn_sched_barrier(0);
#pragma unroll
    for (int i = 0; i < 8; ++i) {
        int task = tid + i * 256;
        int row = task >> 5, part = task & 31;
        uint2 pk; pk.x = pk2(vx[i].x, vx[i].y); pk.y = pk2(vx[i].z, vx[i].w);
        *(uint2*)&A[row * 136 + part * 4] = pk;
    }
    __syncthreads();

    // ---- L0 half 1 (x . W0[0:128]) ; then issue L0 second-half A-frags.
    floatx4 acc[2][4];
    layer_mfma<128, 2, 4, true>(A, 136, lane, a0a, acc);
    __builtin_amdgcn_sched_barrier(0);
    short8 a0b[4][2];
    load_a<4, 2>(wt0, 8, t32, 4, lane, a0b);       // kt 4..7 (ea half)
    __builtin_amdgcn_sched_barrier(0);
    __syncthreads();                               // all waves done reading A(x)

    // ---- overwrite A with ea-part (already in regs)
#pragma unroll
    for (int i = 0; i < 8; ++i) {
        int task = tid + i * 256;
        int row = task >> 5, part = task & 31;
        uint2 pk; pk.x = pk2(ve[i].x, ve[i].y); pk.y = pk2(ve[i].z, ve[i].w);
        *(uint2*)&A[row * 136 + part * 4] = pk;
    }
    __syncthreads();

    // ---- L0 half 2 (accumulate) ; prefetch L1 frags first.
    short8 a1[4][2];
    load_a<4, 2>(wt1, 8, t32, 0, lane, a1);
    __builtin_amdgcn_sched_barrier(0);
    layer_mfma<128, 2, 4, false>(A, 136, lane, a0b, acc);
    store_lds<2, 4>(acc, b0, lane, wave * 32, B, 136, true);     // H1 -> B
    __syncthreads();

    // ---- L1: read B(H1) -> write A(H2). Prefetch L2.
    short8 a2[4][2];
    load_a<4, 2>(wt2, 8, t32, 0, lane, a2);
    __builtin_amdgcn_sched_barrier(0);
    {
        floatx4 acc1[2][4];
        layer_mfma<128, 2, 4, true>(B, 136, lane, a1, acc1);
        store_lds<2, 4>(acc1, b1, lane, wave * 32, A, 136, true);
    }
    __syncthreads();

    // ---- L2: read A(H2) -> write B(H3). Prefetch L3 pass-1 frags (features wave*32, tiles 2w).
    short8 a3a[4][2];
    load_a<4, 2>(wt3, 16, t32, 0, lane, a3a);
    __builtin_amdgcn_sched_barrier(0);
    {
        floatx4 acc2[2][4];
        layer_mfma<128, 2, 4, true>(A, 136, lane, a2, acc2);
        store_lds<2, 4>(acc2, b2, lane, wave * 32, B, 136, true);
    }
    __syncthreads();

    // ---- L3 pass 1: features 0..127 (wave*32). read B(H3) -> G @ A (H2 dead).
    {
        floatx4 acc3[2][4];
        layer_mfma<128, 2, 4, true>(B, 136, lane, a3a, acc3);
        store_lds<2, 4>(acc3, b3, lane, wave * 32, A, 136, true);
    }
    __syncthreads();

    // ---- reduce pass 1 (cols 0..127); prefetch L3 pass-2 frags under it.
    short8 a3b[4][2];
    load_a<4, 2>(wt3, 16, 8 + t32, 0, lane, a3b);   // tiles 8 + 2w -> features 128 + wave*32
    __builtin_amdgcn_sched_barrier(0);
    {
        int colp = tid & 63;          // 64 col-pairs
        int seg  = tid >> 6;          // 4 segments x 16 edges
        int col2 = colp * 2;
        int base = seg * 16;
        float s0 = 0.f, s1 = 0.f;
#pragma unroll 4
        for (int i = 0; i < 16; ++i) {
            int gi = base + i;
            unsigned int u = *(const unsigned int*)&A[gi * 136 + col2];
            s0 += bf2f((unsigned short)u);
            s1 += bf2f((unsigned short)(u >> 16));
            if (i == 15 || ds[gi + 1] != ds[gi]) {
                float* dst = &s[(size_t)ds[gi] * 256 + col2];
                atomicAdd(dst, s0);
                atomicAdd(dst + 1, s1);
                s0 = 0.f; s1 = 0.f;
            }
        }
    }
    __syncthreads();                  // G pass-1 dead

    // ---- L3 pass 2: features 128..255. read B(H3, intact) -> G @ A. bias = b3+128.
    {
        floatx4 acc3[2][4];
        layer_mfma<128, 2, 4, true>(B, 136, lane, a3b, acc3);
        store_lds<2, 4>(acc3, b3 + 128, lane, wave * 32, A, 136, true);
    }
    __syncthreads();

    // ---- reduce pass 2 (cols 128..255)
    {
        int colp = tid & 63;
        int seg  = tid >> 6;
        int col2 = colp * 2;
        int base = seg * 16;
        float s0 = 0.f, s1 = 0.f;
#pragma unroll 4
        for (int i = 0; i < 16; ++i) {
            int gi = base + i;
            unsigned int u = *(const unsigned int*)&A[gi * 136 + col2];
            s0 += bf2f((unsigned short)u);
            s1 += bf2f((unsigned short)(u >> 16));
            if (i == 15 || ds[gi + 1] != ds[gi]) {
                float* dst = &s[(size_t)ds[gi] * 256 + 128 + col2];
                atomicAdd(dst, s0);
                atomicAdd(dst + 1, s1);
                s0 = 0.f; s1 = 0.f;
            }
        }
    }
}

// ---------------- node MLP (16 nodes/block -> 625 blocks) ----------------
__global__ __launch_bounds__(256, 2) void node_kernel(
    const float* __restrict__ x,
    const float* __restrict__ g,
    const float* __restrict__ s,
    const int* __restrict__ cnt,
    const unsigned short* __restrict__ wt0, const float* __restrict__ b0,
    const unsigned short* __restrict__ wt1, const float* __restrict__ b1,
    const unsigned short* __restrict__ wt2, const float* __restrict__ b2,
    const unsigned short* __restrict__ wt3, const float* __restrict__ b3,
    float* __restrict__ out)
{
    // Aliased LDS (17920 B):
    //   Abig [16][424] @0; HsA [16][136] @13568; HsB=@0 (Abig dead after pre-L1 barrier).
    __shared__ __align__(16) char NU[17920];
    unsigned short* Abig = (unsigned short*)NU;
    unsigned short* HsA  = (unsigned short*)(NU + 13568);
    unsigned short* HsB  = (unsigned short*)NU;

    const int tid = threadIdx.x;
    const int node0 = blockIdx.x * 16;   // grid 625 * 16 = 10000 exact

    // x part: cols 0..127 (16 rows x 32 float4 parts = 512 tasks)
#pragma unroll
    for (int i = 0; i < 2; ++i) {
        int task = tid + i * 256;
        int row = task >> 5, part = task & 31;
        float4 v = *(const float4*)(x + (size_t)(node0 + row) * 128 + part * 4);
        uint2 pk; pk.x = pk2(v.x, v.y); pk.y = pk2(v.z, v.w);
        *(uint2*)&Abig[row * 424 + part * 4] = pk;
    }
    // agg part: cols 128..383 (s / max(cnt,1)) (16 rows x 64 parts = 1024 tasks)
#pragma unroll
    for (int i = 0; i < 4; ++i) {
        int task = tid + i * 256;
        int row = task >> 6, part = task & 63;
        int node = node0 + row;
        float c = (float)cnt[node];
        float inv = 1.f / (c > 1.f ? c : 1.f);
        floatx4 v = *(const floatx4*)(s + (size_t)node * 256 + part * 4);
        uint2 pk;
        pk.x = pk2(v[0] * inv, v[1] * inv);
        pk.y = pk2(v[2] * inv, v[3] * inv);
        *(uint2*)&Abig[row * 424 + 128 + part * 4] = pk;
    }
    // global part: cols 384..415 (16 rows x 8 parts = 128 tasks)
    if (tid < 128) {
        int row = tid >> 3, part = tid & 7;
        float4 v = *(const float4*)(g + part * 4);
        uint2 pk; pk.x = pk2(v.x, v.y); pk.y = pk2(v.z, v.w);
        *(uint2*)&Abig[row * 424 + 384 + part * 4] = pk;
    }
    __syncthreads();

    const int lane = tid & 63;
    const int wave = tid >> 6;
    const int t32 = wave * 2;

    // L0 (K=416): streamed A. Prefetch L1 A-frags first.
    short8 a1[4][2];
    load_a<4, 2>(wt1, 8, t32, 0, lane, a1);
    __builtin_amdgcn_sched_barrier(0);
    {
        floatx4 acc[2][1];
        layer_stream<416, 128, 1>(Abig, 424, wt0, lane, wave * 32, acc);
        store_lds<2, 1>(acc, b0, lane, wave * 32, HsA, 136, true);
    }
    __syncthreads();

    short8 a2[4][2];
    load_a<4, 2>(wt2, 8, t32, 0, lane, a2);
    __builtin_amdgcn_sched_barrier(0);
    {
        floatx4 acc[2][1];
        // HsB (@0) overwrites Abig: safe — all Abig reads finished at the pre-L1 barrier.
        layer_mfma<128, 2, 1, true>(HsA, 136, lane, a1, acc);
        store_lds<2, 1>(acc, b1, lane, wave * 32, HsB, 136, true);
    }
    __syncthreads();

    short8 a3[4][2];
    load_a<4, 2>(wt3, 8, t32, 0, lane, a3);
    __builtin_amdgcn_sched_barrier(0);
    {
        floatx4 acc[2][1];
        layer_mfma<128, 2, 1, true>(HsB, 136, lane, a2, acc);
        store_lds<2, 1>(acc, b2, lane, wave * 32, HsA, 136, true);
    }
    __syncthreads();

    {
        floatx4 acc[2][1];
        layer_mfma<128, 2, 1, true>(HsA, 136, lane, a3, acc);
        const int quad = lane >> 4, mrow = lane & 15;
#pragma unroll
        for (int ft = 0; ft < 2; ++ft) {
            int fbase = wave * 32 + ft * 16 + quad * 4;
            float4 bv = *(const float4*)&b3[fbase];
            int node = node0 + mrow;
            float4 o;
            o.x = acc[ft][0][0] + bv.x;
            o.y = acc[ft][0][1] + bv.y;
            o.z = acc[ft][0][2] + bv.z;
            o.w = acc[ft][0][3] + bv.w;
            *(float4*)&out[(size_t)node * 128 + fbase] = o;  // fp32 vectorized
        }
    }
}

extern "C" void kernel_launch(void* const* d_in, const int* in_sizes, int n_in,
                              void* d_out, int out_size, void* d_ws, size_t ws_size,
                              hipStream_t stream)
{
    (void)in_sizes; (void)n_in; (void)out_size; (void)ws_size;

    const float* x  = (const float*)d_in[0];
    const int* eidx = (const int*)d_in[1];
    const float* ea = (const float*)d_in[2];
    const float* g  = (const float*)d_in[3];

    const float* w1[4]  = { (const float*)d_in[4],  (const float*)d_in[6],
                            (const float*)d_in[8],  (const float*)d_in[10] };
    const float* bb1[4] = { (const float*)d_in[5],  (const float*)d_in[7],
                            (const float*)d_in[9],  (const float*)d_in[11] };
    const float* w2[4]  = { (const float*)d_in[12], (const float*)d_in[14],
                            (const float*)d_in[16], (const float*)d_in[18] };
    const float* bb2[4] = { (const float*)d_in[13], (const float*)d_in[15],
                            (const float*)d_in[17], (const float*)d_in[19] };

    char* p = (char*)d_ws;
    unsigned short* wt1_0 = (unsigned short*)p; p += 256 * 128 * 2;
    unsigned short* wt1_1 = (unsigned short*)p; p += 128 * 128 * 2;
    unsigned short* wt1_2 = (unsigned short*)p; p += 128 * 128 * 2;
    unsigned short* wt1_3 = (unsigned short*)p; p += 128 * 256 * 2;
    unsigned short* wt2_0 = (unsigned short*)p; p += 416 * 128 * 2;
    unsigned short* wt2_1 = (unsigned short*)p; p += 128 * 128 * 2;
    unsigned short* wt2_2 = (unsigned short*)p; p += 128 * 128 * 2;
    unsigned short* wt2_3 = (unsigned short*)p; p += 128 * 128 * 2;
    float* s    = (float*)p; p += (size_t)N_NODES * 256 * 4;
    int* cnt    = (int*)p;   p += (size_t)N_NODES * 4;
    int* fill   = (int*)p;   p += (size_t)N_NODES * 4;
    int4* pack  = (int4*)p;  p += (size_t)E_EDGES * 16;

    // zero cnt only; s is zeroed by prep_kernel's third segment
    hipMemsetAsync(cnt, 0, (size_t)N_NODES * 4, stream);

    TArgs ta;
    int bs = 0;
    auto set = [&](int i, const float* src, unsigned short* dst, int K, int Nn, int logN) {
        ta.d[i].src = src; ta.d[i].dst = dst; ta.d[i].nElem = K * Nn;
        ta.d[i].logN = logN; ta.d[i].blockStart = bs;
        bs += (K * Nn + 255) / 256;
    };
    set(0, w1[0], wt1_0, 256, 128, 7);
    set(1, w1[1], wt1_1, 128, 128, 7);
    set(2, w1[2], wt1_2, 128, 128, 7);
    set(3, w1[3], wt1_3, 128, 256, 8);
    set(4, w2[0], wt2_0, 416, 128, 7);
    set(5, w2[1], wt2_1, 128, 128, 7);
    set(6, w2[2], wt2_2, 128, 128, 7);
    set(7, w2[3], wt2_3, 128, 128, 7);

    int histBlocks = E_EDGES / 256;                       // 1250
    int zeroBlocks = (N_NODES * 256 / 4) / 256;           // 2500
    hipLaunchKernelGGL(prep_kernel, dim3(bs + histBlocks + zeroBlocks), dim3(256), 0, stream,
                       ta, eidx, cnt, (float4*)s, bs, bs + histBlocks);
    hipLaunchKernelGGL(scan_kernel, dim3(1), dim3(256), 0, stream, cnt, fill);
    hipLaunchKernelGGL(fill_kernel, dim3(E_EDGES / 256), dim3(256), 0, stream,
                       eidx, fill, pack);

    hipLaunchKernelGGL(edge_kernel, dim3(E_EDGES / 64), dim3(256), 0, stream,
                       x, ea, pack,
                       wt1_0, bb1[0], wt1_1, bb1[1], wt1_2, bb1[2], wt1_3, bb1[3],
                       s);

    hipLaunchKernelGGL(node_kernel, dim3(N_NODES / 16), dim3(256), 0, stream,
                       x, g, s, cnt,
                       wt2_0, bb2[0], wt2_1, bb2[1], wt2_2, bb2[2], wt2_3, bb2[3],
                       (float*)d_out);
}

// Round 6
// 444.141 us; speedup vs baseline: 1.1492x; 1.1492x over previous
//
#include <hip/hip_runtime.h>
#include <hip/hip_bf16.h>

#define E_EDGES 320000
#define N_NODES 10000

typedef __attribute__((ext_vector_type(8))) short short8;
typedef __attribute__((ext_vector_type(4))) float floatx4;

__device__ __forceinline__ float bf2f(unsigned short u) {
    union { unsigned int i; float f; } v; v.i = ((unsigned int)u) << 16; return v.f;
}
// pack two fp32 -> bf16x2 (RNE), low = a
__device__ __forceinline__ unsigned int pk2(float a, float b) {
    float2 t; t.x = a; t.y = b;
    __hip_bfloat162 h = __float22bfloat162_rn(t);
    union { __hip_bfloat162 h; unsigned int u; } c; c.h = h; return c.u;
}

// ---- A-fragment batch load (weights, fragment-tiled in global), kt0 = K-tile base.
// Caller wraps with __builtin_amdgcn_sched_barrier(0) to pin issue position.
template<int KT, int FT>
__device__ __forceinline__ void load_a(const unsigned short* __restrict__ wt, int ntiles, int t0,
                                       int kt0, int lane, short8 (&a)[KT][FT])
{
#pragma unroll
    for (int kt = 0; kt < KT; ++kt)
#pragma unroll
        for (int ft = 0; ft < FT; ++ft)
            a[kt][ft] = *(const short8*)&wt[(size_t)((kt0 + kt) * ntiles + t0 + ft) * 512 + lane * 8];
}

// ---- MFMA layer, SWAPPED operands: A = weights (registers), B = acts (LDS).
// acc[ft][et]: D col=lane&15 -> edge (et*16+mrow), row=quad*4+r -> feature (n0+ft*16+quad*4+r).
// ZERO=false accumulates into acc (split-K).
template<int K, int FT, int ET, bool ZERO>
__device__ __forceinline__ void layer_mfma(const unsigned short* __restrict__ in, int istride,
                                           int lane, const short8 (&a)[K / 32][FT],
                                           floatx4 (&acc)[FT][ET])
{
    constexpr int KT = K / 32;
    const int quad = lane >> 4;
    const int mrow = lane & 15;
    if (ZERO) {
        floatx4 zero = {0.f, 0.f, 0.f, 0.f};
#pragma unroll
        for (int ft = 0; ft < FT; ++ft)
#pragma unroll
            for (int et = 0; et < ET; ++et)
                acc[ft][et] = zero;
    }
#pragma unroll
    for (int kt = 0; kt < KT; ++kt) {
        const int koff = kt * 32 + quad * 8;
        short8 b[ET];
#pragma unroll
        for (int et = 0; et < ET; ++et)
            b[et] = *(const short8*)&in[(et * 16 + mrow) * istride + koff];
#pragma unroll
        for (int ft = 0; ft < FT; ++ft)
#pragma unroll
            for (int et = 0; et < ET; ++et)
                acc[ft][et] = __builtin_amdgcn_mfma_f32_16x16x32_bf16(a[kt][ft], b[et], acc[ft][et], 0, 0, 0);
    }
}

// layer_stream: A (global) and B (LDS) double-buffered depth-1 — for K=416 (A too big for regs).
template<int K, int Nn, int ET>
__device__ __forceinline__ void layer_stream(const unsigned short* __restrict__ in, int istride,
                                             const unsigned short* __restrict__ wt,
                                             int lane, int n0, floatx4 (&acc)[2][ET])
{
    constexpr int KT = K / 32;
    const int quad = lane >> 4;
    const int mrow = lane & 15;

    floatx4 zero = {0.f, 0.f, 0.f, 0.f};
#pragma unroll
    for (int ft = 0; ft < 2; ++ft)
#pragma unroll
        for (int et = 0; et < ET; ++et)
            acc[ft][et] = zero;

    short8 a[2][2];
    short8 b[2][ET];
#pragma unroll
    for (int ft = 0; ft < 2; ++ft)
        a[0][ft] = *(const short8*)&wt[(size_t)((n0 >> 4) + ft) * 512 + lane * 8];
#pragma unroll
    for (int et = 0; et < ET; ++et)
        b[0][et] = *(const short8*)&in[(et * 16 + mrow) * istride + quad * 8];

#pragma unroll
    for (int kt = 0; kt < KT; ++kt) {
        if (kt + 1 < KT) {
            const int nb = (kt + 1) & 1;
            const int koff = (kt + 1) * 32 + quad * 8;
#pragma unroll
            for (int ft = 0; ft < 2; ++ft)
                a[nb][ft] = *(const short8*)&wt[(size_t)((kt + 1) * (Nn >> 4) + (n0 >> 4) + ft) * 512 + lane * 8];
#pragma unroll
            for (int et = 0; et < ET; ++et)
                b[nb][et] = *(const short8*)&in[(et * 16 + mrow) * istride + koff];
        }
#pragma unroll
        for (int ft = 0; ft < 2; ++ft)
#pragma unroll
            for (int et = 0; et < ET; ++et)
                acc[ft][et] = __builtin_amdgcn_mfma_f32_16x16x32_bf16(a[kt & 1][ft], b[kt & 1][et], acc[ft][et], 0, 0, 0);
    }
}

// store D to LDS [edge][feature] bf16: 4 consecutive features per reg-quad -> one ds_write_b64
template<int FT, int ET>
__device__ __forceinline__ void store_lds(floatx4 (&acc)[FT][ET], const float* __restrict__ bias,
                                          int lane, int n0, unsigned short* __restrict__ out, int ostride,
                                          bool relu)
{
    const int quad = lane >> 4, mrow = lane & 15;
#pragma unroll
    for (int ft = 0; ft < FT; ++ft) {
        int fbase = n0 + ft * 16 + quad * 4;
        float4 bv = *(const float4*)&bias[fbase];
#pragma unroll
        for (int et = 0; et < ET; ++et) {
            int edge = et * 16 + mrow;
            float v0 = acc[ft][et][0] + bv.x;
            float v1 = acc[ft][et][1] + bv.y;
            float v2 = acc[ft][et][2] + bv.z;
            float v3 = acc[ft][et][3] + bv.w;
            if (relu) {
                v0 = v0 > 0.f ? v0 : 0.f; v1 = v1 > 0.f ? v1 : 0.f;
                v2 = v2 > 0.f ? v2 : 0.f; v3 = v3 > 0.f ? v3 : 0.f;
            }
            uint2 pk; pk.x = pk2(v0, v1); pk.y = pk2(v2, v3);
            *(uint2*)&out[edge * ostride + fbase] = pk;
        }
    }
}

// ---------------- fused prep: weight repack + degree histogram + s-zeroing ----------------
struct TDesc { const float* src; unsigned short* dst; int nElem; int logN; int blockStart; };
struct TArgs { TDesc d[8]; };

__global__ void prep_kernel(TArgs a, const int* __restrict__ eidx, int* __restrict__ cnt,
                            float4* __restrict__ s4, int histStart, int zeroStart)
{
    int b = blockIdx.x;
    if (b >= zeroStart) {
        // zero s: 2500 blocks x 256 threads x float4 = N_NODES*256 floats exact
        int idx = (b - zeroStart) * 256 + threadIdx.x;
        float4 z = {0.f, 0.f, 0.f, 0.f};
        s4[idx] = z;
        return;
    }
    if (b >= histStart) {
        int e = (b - histStart) * 256 + threadIdx.x;
        if (e < E_EDGES) atomicAdd(&cnt[eidx[E_EDGES + e]], 1);
        return;
    }
    int i = 0;
#pragma unroll
    for (int j = 1; j < 8; ++j)
        if (b >= a.d[j].blockStart) i = j;
    const TDesc t = a.d[i];
    int idx = (b - t.blockStart) * 256 + threadIdx.x;
    if (idx < t.nElem) {
        int n = idx & ((1 << t.logN) - 1);
        int k = idx >> t.logN;
        int ntiles = 1 << (t.logN - 4);
        size_t dsti = ((size_t)(k >> 5) * ntiles + (n >> 4)) * 512
                    + ((k >> 3) & 3) * 128 + (n & 15) * 8 + (k & 7);
        union { float f; unsigned int u; } c; c.f = t.src[idx];
        unsigned int uu = c.u;
        t.dst[dsti] = (unsigned short)((uu + 0x7fffu + ((uu >> 16) & 1u)) >> 16);
    }
}

__global__ void scan_kernel(const int* __restrict__ cnt, int* __restrict__ fill)
{
    __shared__ int partial[256];
    const int CH = 40;                      // 256*40 = 10240 >= N_NODES
    int tid = threadIdx.x;
    int base = tid * CH;
    int local[CH];
    int sum = 0;
#pragma unroll
    for (int j = 0; j < CH; ++j) {
        int idx = base + j;
        int c = (idx < N_NODES) ? cnt[idx] : 0;
        local[j] = c;
        sum += c;
    }
    partial[tid] = sum;
    __syncthreads();
    for (int o = 1; o < 256; o <<= 1) {
        int v = (tid >= o) ? partial[tid - o] : 0;
        __syncthreads();
        partial[tid] += v;
        __syncthreads();
    }
    int run = partial[tid] - sum;
#pragma unroll
    for (int j = 0; j < CH; ++j) {
        int idx = base + j;
        if (idx < N_NODES) fill[idx] = run;
        run += local[j];
    }
}

// pack (edge, src, dst) into ONE int4 store: 1 random cacheline per edge instead of 3
__global__ void fill_kernel(const int* __restrict__ eidx, int* __restrict__ fill,
                            int4* __restrict__ pack)
{
    int e = blockIdx.x * 256 + threadIdx.x;
    int c = eidx[E_EDGES + e];
    int r = eidx[e];
    int pos = atomicAdd(&fill[c], 1);
    pack[pos] = make_int4(e, r, c, 0);
}

// ---------------- edge MLP: 64 edges/block, split-K L0 + split-feature L3 ----------------
// LDS: region A @0 [64][136], region B @17408 [64][136]. Total 34816 B + 768 idx -> 4 blocks/CU.
// Spill-safe schedule: never more than ~112 VGPRs live (vx and ve never coexist;
// ve lives only across the L0h1 MFMA cluster).
__global__ __launch_bounds__(256, 4) void edge_kernel(
    const float* __restrict__ x,
    const float* __restrict__ ea,
    const int4* __restrict__ pack,
    const unsigned short* __restrict__ wt0, const float* __restrict__ b0,
    const unsigned short* __restrict__ wt1, const float* __restrict__ b1,
    const unsigned short* __restrict__ wt2, const float* __restrict__ b2,
    const unsigned short* __restrict__ wt3, const float* __restrict__ b3,
    float* __restrict__ s)
{
    __shared__ __align__(16) char U[34816];
    __shared__ int es[64];
    __shared__ int rs[64];
    __shared__ int ds[64];

    unsigned short* A = (unsigned short*)U;            // x-half, H1, H3
    unsigned short* B = (unsigned short*)(U + 17408);  // ea-half, H2, G

    const int tid = threadIdx.x;
    const int p0 = blockIdx.x * 64;

    if (tid < 64) {
        int4 pr = pack[p0 + tid];
        es[tid] = pr.x; rs[tid] = pr.y; ds[tid] = pr.z;
    }
    __syncthreads();

    const int lane = tid & 63;
    const int wave = tid >> 6;
    const int t32 = wave * 2;   // feature-tile base (32 features/wave, L0-L2)

    // ---- Phase S: batch x loads; write x-half -> A.
    {
        float4 vx[8];
#pragma unroll
        for (int i = 0; i < 8; ++i) {              // 64 rows x 32 parts
            int task = tid + i * 256;
            int row = task >> 5, part = task & 31;
            vx[i] = *(const float4*)(x + (size_t)rs[row] * 128 + part * 4);
        }
        __builtin_amdgcn_sched_barrier(0);
#pragma unroll
        for (int i = 0; i < 8; ++i) {
            int task = tid + i * 256;
            int row = task >> 5, part = task & 31;
            uint2 pk; pk.x = pk2(vx[i].x, vx[i].y); pk.y = pk2(vx[i].z, vx[i].w);
            *(uint2*)&A[row * 136 + part * 4] = pk;
        }
    }
    short8 a0a[4][2];
    load_a<4, 2>(wt0, 8, t32, 0, lane, a0a);       // L0 weights kt 0..3 (x half)
    __builtin_amdgcn_sched_barrier(0);
    __syncthreads();

    // ---- L0 half 1 (x . W0[0:128]): issue ea loads first (latency hides under MFMAs),
    //      then MFMA cluster, then pack ea -> B, then load second-half weights.
    floatx4 acc[2][4];
    {
        float4 ve[8];
#pragma unroll
        for (int i = 0; i < 8; ++i) {
            int task = tid + i * 256;
            int row = task >> 5, part = task & 31;
            ve[i] = *(const float4*)(ea + (size_t)es[row] * 128 + part * 4);
        }
        __builtin_amdgcn_sched_barrier(0);
        layer_mfma<128, 2, 4, true>(A, 136, lane, a0a, acc);
        __builtin_amdgcn_sched_barrier(0);
#pragma unroll
        for (int i = 0; i < 8; ++i) {
            int task = tid + i * 256;
            int row = task >> 5, part = task & 31;
            uint2 pk; pk.x = pk2(ve[i].x, ve[i].y); pk.y = pk2(ve[i].z, ve[i].w);
            *(uint2*)&B[row * 136 + part * 4] = pk;
        }
    }
    short8 a0b[4][2];
    load_a<4, 2>(wt0, 8, t32, 4, lane, a0b);       // kt 4..7 (ea half)
    __builtin_amdgcn_sched_barrier(0);
    __syncthreads();

    // ---- L0 half 2 (accumulate over B=ea); prefetch L1 frags; H1 -> A (x-half dead).
    short8 a1[4][2];
    load_a<4, 2>(wt1, 8, t32, 0, lane, a1);
    __builtin_amdgcn_sched_barrier(0);
    layer_mfma<128, 2, 4, false>(B, 136, lane, a0b, acc);
    store_lds<2, 4>(acc, b0, lane, wave * 32, A, 136, true);
    __syncthreads();

    // ---- L1: read A(H1) -> write B(H2). Prefetch L2.
    short8 a2[4][2];
    load_a<4, 2>(wt2, 8, t32, 0, lane, a2);
    __builtin_amdgcn_sched_barrier(0);
    {
        floatx4 acc1[2][4];
        layer_mfma<128, 2, 4, true>(A, 136, lane, a1, acc1);
        store_lds<2, 4>(acc1, b1, lane, wave * 32, B, 136, true);
    }
    __syncthreads();

    // ---- L2: read B(H2) -> write A(H3). Prefetch L3 pass-1 frags.
    short8 a3a[4][2];
    load_a<4, 2>(wt3, 16, t32, 0, lane, a3a);
    __builtin_amdgcn_sched_barrier(0);
    {
        floatx4 acc2[2][4];
        layer_mfma<128, 2, 4, true>(B, 136, lane, a2, acc2);
        store_lds<2, 4>(acc2, b2, lane, wave * 32, A, 136, true);
    }
    __syncthreads();

    // ---- L3 pass 1: features 0..127. read A(H3) -> G @ B (H2 dead).
    {
        floatx4 acc3[2][4];
        layer_mfma<128, 2, 4, true>(A, 136, lane, a3a, acc3);
        store_lds<2, 4>(acc3, b3, lane, wave * 32, B, 136, true);
    }
    __syncthreads();

    // ---- reduce pass 1 (cols 0..127); prefetch L3 pass-2 frags under it.
    short8 a3b[4][2];
    load_a<4, 2>(wt3, 16, 8 + t32, 0, lane, a3b);   // tiles 8 + 2w -> features 128 + wave*32
    __builtin_amdgcn_sched_barrier(0);
    {
        int colp = tid & 63;          // 64 col-pairs
        int seg  = tid >> 6;          // 4 segments x 16 edges
        int col2 = colp * 2;
        int base = seg * 16;
        float s0 = 0.f, s1 = 0.f;
#pragma unroll 4
        for (int i = 0; i < 16; ++i) {
            int gi = base + i;
            unsigned int u = *(const unsigned int*)&B[gi * 136 + col2];
            s0 += bf2f((unsigned short)u);
            s1 += bf2f((unsigned short)(u >> 16));
            if (i == 15 || ds[gi + 1] != ds[gi]) {
                float* dst = &s[(size_t)ds[gi] * 256 + col2];
                atomicAdd(dst, s0);
                atomicAdd(dst + 1, s1);
                s0 = 0.f; s1 = 0.f;
            }
        }
    }
    __syncthreads();                  // G pass-1 dead

    // ---- L3 pass 2: features 128..255. read A(H3, intact) -> G @ B. bias = b3+128.
    {
        floatx4 acc3[2][4];
        layer_mfma<128, 2, 4, true>(A, 136, lane, a3b, acc3);
        store_lds<2, 4>(acc3, b3 + 128, lane, wave * 32, B, 136, true);
    }
    __syncthreads();

    // ---- reduce pass 2 (cols 128..255)
    {
        int colp = tid & 63;
        int seg  = tid >> 6;
        int col2 = colp * 2;
        int base = seg * 16;
        float s0 = 0.f, s1 = 0.f;
#pragma unroll 4
        for (int i = 0; i < 16; ++i) {
            int gi = base + i;
            unsigned int u = *(const unsigned int*)&B[gi * 136 + col2];
            s0 += bf2f((unsigned short)u);
            s1 += bf2f((unsigned short)(u >> 16));
            if (i == 15 || ds[gi + 1] != ds[gi]) {
                float* dst = &s[(size_t)ds[gi] * 256 + 128 + col2];
                atomicAdd(dst, s0);
                atomicAdd(dst + 1, s1);
                s0 = 0.f; s1 = 0.f;
            }
        }
    }
}

// ---------------- node MLP (16 nodes/block -> 625 blocks) ----------------
__global__ __launch_bounds__(256, 2) void node_kernel(
    const float* __restrict__ x,
    const float* __restrict__ g,
    const float* __restrict__ s,
    const int* __restrict__ cnt,
    const unsigned short* __restrict__ wt0, const float* __restrict__ b0,
    const unsigned short* __restrict__ wt1, const float* __restrict__ b1,
    const unsigned short* __restrict__ wt2, const float* __restrict__ b2,
    const unsigned short* __restrict__ wt3, const float* __restrict__ b3,
    float* __restrict__ out)
{
    // Aliased LDS (17920 B):
    //   Abig [16][424] @0; HsA [16][136] @13568; HsB=@0 (Abig dead after pre-L1 barrier).
    __shared__ __align__(16) char NU[17920];
    unsigned short* Abig = (unsigned short*)NU;
    unsigned short* HsA  = (unsigned short*)(NU + 13568);
    unsigned short* HsB  = (unsigned short*)NU;

    const int tid = threadIdx.x;
    const int node0 = blockIdx.x * 16;   // grid 625 * 16 = 10000 exact

    // x part: cols 0..127 (16 rows x 32 float4 parts = 512 tasks)
#pragma unroll
    for (int i = 0; i < 2; ++i) {
        int task = tid + i * 256;
        int row = task >> 5, part = task & 31;
        float4 v = *(const float4*)(x + (size_t)(node0 + row) * 128 + part * 4);
        uint2 pk; pk.x = pk2(v.x, v.y); pk.y = pk2(v.z, v.w);
        *(uint2*)&Abig[row * 424 + part * 4] = pk;
    }
    // agg part: cols 128..383 (s / max(cnt,1)) (16 rows x 64 parts = 1024 tasks)
#pragma unroll
    for (int i = 0; i < 4; ++i) {
        int task = tid + i * 256;
        int row = task >> 6, part = task & 63;
        int node = node0 + row;
        float c = (float)cnt[node];
        float inv = 1.f / (c > 1.f ? c : 1.f);
        floatx4 v = *(const floatx4*)(s + (size_t)node * 256 + part * 4);
        uint2 pk;
        pk.x = pk2(v[0] * inv, v[1] * inv);
        pk.y = pk2(v[2] * inv, v[3] * inv);
        *(uint2*)&Abig[row * 424 + 128 + part * 4] = pk;
    }
    // global part: cols 384..415 (16 rows x 8 parts = 128 tasks)
    if (tid < 128) {
        int row = tid >> 3, part = tid & 7;
        float4 v = *(const float4*)(g + part * 4);
        uint2 pk; pk.x = pk2(v.x, v.y); pk.y = pk2(v.z, v.w);
        *(uint2*)&Abig[row * 424 + 384 + part * 4] = pk;
    }
    __syncthreads();

    const int lane = tid & 63;
    const int wave = tid >> 6;
    const int t32 = wave * 2;

    // L0 (K=416): streamed A. Prefetch L1 A-frags first.
    short8 a1[4][2];
    load_a<4, 2>(wt1, 8, t32, 0, lane, a1);
    __builtin_amdgcn_sched_barrier(0);
    {
        floatx4 acc[2][1];
        layer_stream<416, 128, 1>(Abig, 424, wt0, lane, wave * 32, acc);
        store_lds<2, 1>(acc, b0, lane, wave * 32, HsA, 136, true);
    }
    __syncthreads();

    short8 a2[4][2];
    load_a<4, 2>(wt2, 8, t32, 0, lane, a2);
    __builtin_amdgcn_sched_barrier(0);
    {
        floatx4 acc[2][1];
        // HsB (@0) overwrites Abig: safe — all Abig reads finished at the pre-L1 barrier.
        layer_mfma<128, 2, 1, true>(HsA, 136, lane, a1, acc);
        store_lds<2, 1>(acc, b1, lane, wave * 32, HsB, 136, true);
    }
    __syncthreads();

    short8 a3[4][2];
    load_a<4, 2>(wt3, 8, t32, 0, lane, a3);
    __builtin_amdgcn_sched_barrier(0);
    {
        floatx4 acc[2][1];
        layer_mfma<128, 2, 1, true>(HsB, 136, lane, a2, acc);
        store_lds<2, 1>(acc, b2, lane, wave * 32, HsA, 136, true);
    }
    __syncthreads();

    {
        floatx4 acc[2][1];
        layer_mfma<128, 2, 1, true>(HsA, 136, lane, a3, acc);
        const int quad = lane >> 4, mrow = lane & 15;
#pragma unroll
        for (int ft = 0; ft < 2; ++ft) {
            int fbase = wave * 32 + ft * 16 + quad * 4;
            float4 bv = *(const float4*)&b3[fbase];
            int node = node0 + mrow;
            float4 o;
            o.x = acc[ft][0][0] + bv.x;
            o.y = acc[ft][0][1] + bv.y;
            o.z = acc[ft][0][2] + bv.z;
            o.w = acc[ft][0][3] + bv.w;
            *(float4*)&out[(size_t)node * 128 + fbase] = o;  // fp32 vectorized
        }
    }
}

extern "C" void kernel_launch(void* const* d_in, const int* in_sizes, int n_in,
                              void* d_out, int out_size, void* d_ws, size_t ws_size,
                              hipStream_t stream)
{
    (void)in_sizes; (void)n_in; (void)out_size; (void)ws_size;

    const float* x  = (const float*)d_in[0];
    const int* eidx = (const int*)d_in[1];
    const float* ea = (const float*)d_in[2];
    const float* g  = (const float*)d_in[3];

    const float* w1[4]  = { (const float*)d_in[4],  (const float*)d_in[6],
                            (const float*)d_in[8],  (const float*)d_in[10] };
    const float* bb1[4] = { (const float*)d_in[5],  (const float*)d_in[7],
                            (const float*)d_in[9],  (const float*)d_in[11] };
    const float* w2[4]  = { (const float*)d_in[12], (const float*)d_in[14],
                            (const float*)d_in[16], (const float*)d_in[18] };
    const float* bb2[4] = { (const float*)d_in[13], (const float*)d_in[15],
                            (const float*)d_in[17], (const float*)d_in[19] };

    char* p = (char*)d_ws;
    unsigned short* wt1_0 = (unsigned short*)p; p += 256 * 128 * 2;
    unsigned short* wt1_1 = (unsigned short*)p; p += 128 * 128 * 2;
    unsigned short* wt1_2 = (unsigned short*)p; p += 128 * 128 * 2;
    unsigned short* wt1_3 = (unsigned short*)p; p += 128 * 256 * 2;
    unsigned short* wt2_0 = (unsigned short*)p; p += 416 * 128 * 2;
    unsigned short* wt2_1 = (unsigned short*)p; p += 128 * 128 * 2;
    unsigned short* wt2_2 = (unsigned short*)p; p += 128 * 128 * 2;
    unsigned short* wt2_3 = (unsigned short*)p; p += 128 * 128 * 2;
    float* s    = (float*)p; p += (size_t)N_NODES * 256 * 4;
    int* cnt    = (int*)p;   p += (size_t)N_NODES * 4;
    int* fill   = (int*)p;   p += (size_t)N_NODES * 4;
    int4* pack  = (int4*)p;  p += (size_t)E_EDGES * 16;

    // zero cnt only; s is zeroed by prep_kernel's third segment
    (void)hipMemsetAsync(cnt, 0, (size_t)N_NODES * 4, stream);

    TArgs ta;
    int bs = 0;
    auto set = [&](int i, const float* src, unsigned short* dst, int K, int Nn, int logN) {
        ta.d[i].src = src; ta.d[i].dst = dst; ta.d[i].nElem = K * Nn;
        ta.d[i].logN = logN; ta.d[i].blockStart = bs;
        bs += (K * Nn + 255) / 256;
    };
    set(0, w1[0], wt1_0, 256, 128, 7);
    set(1, w1[1], wt1_1, 128, 128, 7);
    set(2, w1[2], wt1_2, 128, 128, 7);
    set(3, w1[3], wt1_3, 128, 256, 8);
    set(4, w2[0], wt2_0, 416, 128, 7);
    set(5, w2[1], wt2_1, 128, 128, 7);
    set(6, w2[2], wt2_2, 128, 128, 7);
    set(7, w2[3], wt2_3, 128, 128, 7);

    int histBlocks = E_EDGES / 256;                       // 1250
    int zeroBlocks = (N_NODES * 256 / 4) / 256;           // 2500
    hipLaunchKernelGGL(prep_kernel, dim3(bs + histBlocks + zeroBlocks), dim3(256), 0, stream,
                       ta, eidx, cnt, (float4*)s, bs, bs + histBlocks);
    hipLaunchKernelGGL(scan_kernel, dim3(1), dim3(256), 0, stream, cnt, fill);
    hipLaunchKernelGGL(fill_kernel, dim3(E_EDGES / 256), dim3(256), 0, stream,
                       eidx, fill, pack);

    hipLaunchKernelGGL(edge_kernel, dim3(E_EDGES / 64), dim3(256), 0, stream,
                       x, ea, pack,
                       wt1_0, bb1[0], wt1_1, bb1[1], wt1_2, bb1[2], wt1_3, bb1[3],
                       s);

    hipLaunchKernelGGL(node_kernel, dim3(N_NODES / 16), dim3(256), 0, stream,
                       x, g, s, cnt,
                       wt2_0, bb2[0], wt2_1, bb2[1], wt2_2, bb2[2], wt2_3, bb2[3],
                       (float*)d_out);
}

// Round 7
// 399.596 us; speedup vs baseline: 1.2773x; 1.1115x over previous
//
#include <hip/hip_runtime.h>
#include <hip/hip_bf16.h>

#define E_EDGES 320000
#define N_NODES 10000

typedef __attribute__((ext_vector_type(8))) short short8;
typedef __attribute__((ext_vector_type(4))) float floatx4;

__device__ __forceinline__ float bf2f(unsigned short u) {
    union { unsigned int i; float f; } v; v.i = ((unsigned int)u) << 16; return v.f;
}
// pack two fp32 -> bf16x2 (RNE), low = a
__device__ __forceinline__ unsigned int pk2(float a, float b) {
    float2 t; t.x = a; t.y = b;
    __hip_bfloat162 h = __float22bfloat162_rn(t);
    union { __hip_bfloat162 h; unsigned int u; } c; c.h = h; return c.u;
}

// ---- A-fragment batch load (weights, fragment-tiled in global), kt0 = K-tile base.
// Caller wraps with __builtin_amdgcn_sched_barrier(0) to pin issue position.
template<int KT, int FT>
__device__ __forceinline__ void load_a(const unsigned short* __restrict__ wt, int ntiles, int t0,
                                       int kt0, int lane, short8 (&a)[KT][FT])
{
#pragma unroll
    for (int kt = 0; kt < KT; ++kt)
#pragma unroll
        for (int ft = 0; ft < FT; ++ft)
            a[kt][ft] = *(const short8*)&wt[(size_t)((kt0 + kt) * ntiles + t0 + ft) * 512 + lane * 8];
}

// ---- MFMA layer, SWAPPED operands: A = weights (registers), B = acts (LDS).
// acc[ft][et]: D col=lane&15 -> edge (et*16+mrow), row=quad*4+r -> feature (n0+ft*16+quad*4+r).
// ZERO=false accumulates into acc (split-K).
template<int K, int FT, int ET, bool ZERO>
__device__ __forceinline__ void layer_mfma(const unsigned short* __restrict__ in, int istride,
                                           int lane, const short8 (&a)[K / 32][FT],
                                           floatx4 (&acc)[FT][ET])
{
    constexpr int KT = K / 32;
    const int quad = lane >> 4;
    const int mrow = lane & 15;
    if (ZERO) {
        floatx4 zero = {0.f, 0.f, 0.f, 0.f};
#pragma unroll
        for (int ft = 0; ft < FT; ++ft)
#pragma unroll
            for (int et = 0; et < ET; ++et)
                acc[ft][et] = zero;
    }
#pragma unroll
    for (int kt = 0; kt < KT; ++kt) {
        const int koff = kt * 32 + quad * 8;
        short8 b[ET];
#pragma unroll
        for (int et = 0; et < ET; ++et)
            b[et] = *(const short8*)&in[(et * 16 + mrow) * istride + koff];
#pragma unroll
        for (int ft = 0; ft < FT; ++ft)
#pragma unroll
            for (int et = 0; et < ET; ++et)
                acc[ft][et] = __builtin_amdgcn_mfma_f32_16x16x32_bf16(a[kt][ft], b[et], acc[ft][et], 0, 0, 0);
    }
}

// layer_stream: A (global) and B (LDS) double-buffered depth-1 — for K=416 (A too big for regs).
template<int K, int Nn, int ET>
__device__ __forceinline__ void layer_stream(const unsigned short* __restrict__ in, int istride,
                                             const unsigned short* __restrict__ wt,
                                             int lane, int n0, floatx4 (&acc)[2][ET])
{
    constexpr int KT = K / 32;
    const int quad = lane >> 4;
    const int mrow = lane & 15;

    floatx4 zero = {0.f, 0.f, 0.f, 0.f};
#pragma unroll
    for (int ft = 0; ft < 2; ++ft)
#pragma unroll
        for (int et = 0; et < ET; ++et)
            acc[ft][et] = zero;

    short8 a[2][2];
    short8 b[2][ET];
#pragma unroll
    for (int ft = 0; ft < 2; ++ft)
        a[0][ft] = *(const short8*)&wt[(size_t)((n0 >> 4) + ft) * 512 + lane * 8];
#pragma unroll
    for (int et = 0; et < ET; ++et)
        b[0][et] = *(const short8*)&in[(et * 16 + mrow) * istride + quad * 8];

#pragma unroll
    for (int kt = 0; kt < KT; ++kt) {
        if (kt + 1 < KT) {
            const int nb = (kt + 1) & 1;
            const int koff = (kt + 1) * 32 + quad * 8;
#pragma unroll
            for (int ft = 0; ft < 2; ++ft)
                a[nb][ft] = *(const short8*)&wt[(size_t)((kt + 1) * (Nn >> 4) + (n0 >> 4) + ft) * 512 + lane * 8];
#pragma unroll
            for (int et = 0; et < ET; ++et)
                b[nb][et] = *(const short8*)&in[(et * 16 + mrow) * istride + koff];
        }
#pragma unroll
        for (int ft = 0; ft < 2; ++ft)
#pragma unroll
            for (int et = 0; et < ET; ++et)
                acc[ft][et] = __builtin_amdgcn_mfma_f32_16x16x32_bf16(a[kt & 1][ft], b[kt & 1][et], acc[ft][et], 0, 0, 0);
    }
}

// store D to LDS [edge][feature] bf16: 4 consecutive features per reg-quad -> one ds_write_b64
template<int FT, int ET>
__device__ __forceinline__ void store_lds(floatx4 (&acc)[FT][ET], const float* __restrict__ bias,
                                          int lane, int n0, unsigned short* __restrict__ out, int ostride,
                                          bool relu)
{
    const int quad = lane >> 4, mrow = lane & 15;
#pragma unroll
    for (int ft = 0; ft < FT; ++ft) {
        int fbase = n0 + ft * 16 + quad * 4;
        float4 bv = *(const float4*)&bias[fbase];
#pragma unroll
        for (int et = 0; et < ET; ++et) {
            int edge = et * 16 + mrow;
            float v0 = acc[ft][et][0] + bv.x;
            float v1 = acc[ft][et][1] + bv.y;
            float v2 = acc[ft][et][2] + bv.z;
            float v3 = acc[ft][et][3] + bv.w;
            if (relu) {
                v0 = v0 > 0.f ? v0 : 0.f; v1 = v1 > 0.f ? v1 : 0.f;
                v2 = v2 > 0.f ? v2 : 0.f; v3 = v3 > 0.f ? v3 : 0.f;
            }
            uint2 pk; pk.x = pk2(v0, v1); pk.y = pk2(v2, v3);
            *(uint2*)&out[edge * ostride + fbase] = pk;
        }
    }
}

// ---------------- fused prep: weight repack + degree histogram + s-zeroing ----------------
struct TDesc { const float* src; unsigned short* dst; int nElem; int logN; int blockStart; };
struct TArgs { TDesc d[8]; };

__global__ void prep_kernel(TArgs a, const int* __restrict__ eidx, int* __restrict__ cnt,
                            float4* __restrict__ s4, int histStart, int zeroStart)
{
    int b = blockIdx.x;
    if (b >= zeroStart) {
        // zero s: 2500 blocks x 256 threads x float4 = N_NODES*256 floats exact
        int idx = (b - zeroStart) * 256 + threadIdx.x;
        float4 z = {0.f, 0.f, 0.f, 0.f};
        s4[idx] = z;
        return;
    }
    if (b >= histStart) {
        int e = (b - histStart) * 256 + threadIdx.x;
        if (e < E_EDGES) atomicAdd(&cnt[eidx[E_EDGES + e]], 1);
        return;
    }
    int i = 0;
#pragma unroll
    for (int j = 1; j < 8; ++j)
        if (b >= a.d[j].blockStart) i = j;
    const TDesc t = a.d[i];
    int idx = (b - t.blockStart) * 256 + threadIdx.x;
    if (idx < t.nElem) {
        int n = idx & ((1 << t.logN) - 1);
        int k = idx >> t.logN;
        int ntiles = 1 << (t.logN - 4);
        size_t dsti = ((size_t)(k >> 5) * ntiles + (n >> 4)) * 512
                    + ((k >> 3) & 3) * 128 + (n & 15) * 8 + (k & 7);
        union { float f; unsigned int u; } c; c.f = t.src[idx];
        unsigned int uu = c.u;
        t.dst[dsti] = (unsigned short)((uu + 0x7fffu + ((uu >> 16) & 1u)) >> 16);
    }
}

__global__ void scan_kernel(const int* __restrict__ cnt, int* __restrict__ fill)
{
    __shared__ int partial[256];
    const int CH = 40;                      // 256*40 = 10240 >= N_NODES
    int tid = threadIdx.x;
    int base = tid * CH;
    int local[CH];
    int sum = 0;
#pragma unroll
    for (int j = 0; j < CH; ++j) {
        int idx = base + j;
        int c = (idx < N_NODES) ? cnt[idx] : 0;
        local[j] = c;
        sum += c;
    }
    partial[tid] = sum;
    __syncthreads();
    for (int o = 1; o < 256; o <<= 1) {
        int v = (tid >= o) ? partial[tid - o] : 0;
        __syncthreads();
        partial[tid] += v;
        __syncthreads();
    }
    int run = partial[tid] - sum;
#pragma unroll
    for (int j = 0; j < CH; ++j) {
        int idx = base + j;
        if (idx < N_NODES) fill[idx] = run;
        run += local[j];
    }
}

// pack (edge, src, dst) into ONE int4 store: 1 random cacheline per edge instead of 3
__global__ void fill_kernel(const int* __restrict__ eidx, int* __restrict__ fill,
                            int4* __restrict__ pack)
{
    int e = blockIdx.x * 256 + threadIdx.x;
    int c = eidx[E_EDGES + e];
    int r = eidx[e];
    int pos = atomicAdd(&fill[c], 1);
    pack[pos] = make_int4(e, r, c, 0);
}

// ---------------- edge MLP: 64 edges/block, two-half L0, ping-pong LDS, split-feature L3 ----
// LDS: Hx [64][136] @0, He [64][136] @17408. Total 34816 B + 768 idx -> 4 blocks/CU by LDS.
// Overlay chain: Hx: x-half -> H1 -> H3 ; He: ea-half -> H2 -> G1/G2.
// Round-2 register schedule (bound (256,3) => no forced spill; if natural alloc <=128
// the HW still runs 4 blocks/CU thanks to the smaller LDS).
__global__ __launch_bounds__(256, 3) void edge_kernel(
    const float* __restrict__ x,
    const float* __restrict__ ea,
    const int4* __restrict__ pack,
    const unsigned short* __restrict__ wt0, const float* __restrict__ b0,
    const unsigned short* __restrict__ wt1, const float* __restrict__ b1,
    const unsigned short* __restrict__ wt2, const float* __restrict__ b2,
    const unsigned short* __restrict__ wt3, const float* __restrict__ b3,
    float* __restrict__ s)
{
    __shared__ __align__(16) char U[34816];
    __shared__ int es[64];
    __shared__ int rs[64];
    __shared__ int ds[64];

    unsigned short* Hx = (unsigned short*)U;            // x-half, H1, H3
    unsigned short* He = (unsigned short*)(U + 17408);  // ea-half, H2, G1/G2

    const int tid = threadIdx.x;
    const int p0 = blockIdx.x * 64;

    if (tid < 64) {
        int4 pr = pack[p0 + tid];
        es[tid] = pr.x; rs[tid] = pr.y; ds[tid] = pr.z;
    }
    __syncthreads();

    const int lane = tid & 63;
    const int wave = tid >> 6;
    const int t32 = wave * 2;   // feature-tile base (32 features/wave, L0-L2)

    // ---- Phase S: batch-issue ALL 16 staging loads (round-2 proven), then a0a, then writes.
    {
        float4 v[16];
#pragma unroll
        for (int i = 0; i < 8; ++i) {              // x: 64 rows x 32 parts
            int task = tid + i * 256;
            int row = task >> 5, part = task & 31;
            v[i] = *(const float4*)(x + (size_t)rs[row] * 128 + part * 4);
        }
#pragma unroll
        for (int i = 0; i < 8; ++i) {              // ea: 64 rows x 32 parts
            int task = tid + i * 256;
            int row = task >> 5, part = task & 31;
            v[8 + i] = *(const float4*)(ea + (size_t)es[row] * 128 + part * 4);
        }
        __builtin_amdgcn_sched_barrier(0);
#pragma unroll
        for (int i = 0; i < 8; ++i) {
            int task = tid + i * 256;
            int row = task >> 5, part = task & 31;
            uint2 pk; pk.x = pk2(v[i].x, v[i].y); pk.y = pk2(v[i].z, v[i].w);
            *(uint2*)&Hx[row * 136 + part * 4] = pk;
        }
#pragma unroll
        for (int i = 0; i < 8; ++i) {
            int task = tid + i * 256;
            int row = task >> 5, part = task & 31;
            uint2 pk; pk.x = pk2(v[8 + i].x, v[8 + i].y); pk.y = pk2(v[8 + i].z, v[8 + i].w);
            *(uint2*)&He[row * 136 + part * 4] = pk;
        }
    }
    short8 a0a[4][2];
    load_a<4, 2>(wt0, 8, t32, 0, lane, a0a);       // L0 weights kt 0..3 (x half)
    __builtin_amdgcn_sched_barrier(0);
    __syncthreads();

    // ---- L0: kt0-3 over Hx, kt4-7 over He (accumulate). a0b prefetch under half 1.
    floatx4 acc[2][4];
    short8 a0b[4][2];
    load_a<4, 2>(wt0, 8, t32, 4, lane, a0b);       // kt 4..7 (ea half)
    __builtin_amdgcn_sched_barrier(0);
    layer_mfma<128, 2, 4, true>(Hx, 136, lane, a0a, acc);
    layer_mfma<128, 2, 4, false>(He, 136, lane, a0b, acc);
    short8 a1[4][2];
    load_a<4, 2>(wt1, 8, t32, 0, lane, a1);        // L1 prefetch (hides under barrier+store)
    __builtin_amdgcn_sched_barrier(0);
    __syncthreads();                               // ALL waves done reading Hx/He
    store_lds<2, 4>(acc, b0, lane, wave * 32, Hx, 136, true);   // H1 over Hx
    __syncthreads();

    // ---- L1: read Hx(H1) -> write He(H2). Prefetch L2.
    short8 a2[4][2];
    load_a<4, 2>(wt2, 8, t32, 0, lane, a2);
    __builtin_amdgcn_sched_barrier(0);
    {
        floatx4 acc1[2][4];
        layer_mfma<128, 2, 4, true>(Hx, 136, lane, a1, acc1);
        store_lds<2, 4>(acc1, b1, lane, wave * 32, He, 136, true);
    }
    __syncthreads();

    // ---- L2: read He(H2) -> write Hx(H3). Prefetch L3 pass-1 frags.
    short8 a3a[4][2];
    load_a<4, 2>(wt3, 16, t32, 0, lane, a3a);
    __builtin_amdgcn_sched_barrier(0);
    {
        floatx4 acc2[2][4];
        layer_mfma<128, 2, 4, true>(He, 136, lane, a2, acc2);
        store_lds<2, 4>(acc2, b2, lane, wave * 32, Hx, 136, true);
    }
    __syncthreads();

    // ---- L3 pass 1: features 0..127. read Hx(H3) -> G1 @ He (H2 dead).
    {
        floatx4 acc3[2][4];
        layer_mfma<128, 2, 4, true>(Hx, 136, lane, a3a, acc3);
        store_lds<2, 4>(acc3, b3, lane, wave * 32, He, 136, true);
    }
    __syncthreads();

    // ---- reduce pass 1 (cols 0..127); prefetch L3 pass-2 frags under it.
    short8 a3b[4][2];
    load_a<4, 2>(wt3, 16, 8 + t32, 0, lane, a3b);   // tiles 8 + 2w -> features 128 + wave*32
    __builtin_amdgcn_sched_barrier(0);
    {
        int colp = tid & 63;          // 64 col-pairs
        int seg  = tid >> 6;          // 4 segments x 16 edges
        int col2 = colp * 2;
        int base = seg * 16;
        float s0 = 0.f, s1 = 0.f;
#pragma unroll 4
        for (int i = 0; i < 16; ++i) {
            int gi = base + i;
            unsigned int u = *(const unsigned int*)&He[gi * 136 + col2];
            s0 += bf2f((unsigned short)u);
            s1 += bf2f((unsigned short)(u >> 16));
            if (i == 15 || ds[gi + 1] != ds[gi]) {
                float* dst = &s[(size_t)ds[gi] * 256 + col2];
                atomicAdd(dst, s0);
                atomicAdd(dst + 1, s1);
                s0 = 0.f; s1 = 0.f;
            }
        }
    }
    __syncthreads();                  // G1 dead

    // ---- L3 pass 2: features 128..255. read Hx(H3, intact) -> G2 @ He. bias = b3+128.
    {
        floatx4 acc3[2][4];
        layer_mfma<128, 2, 4, true>(Hx, 136, lane, a3b, acc3);
        store_lds<2, 4>(acc3, b3 + 128, lane, wave * 32, He, 136, true);
    }
    __syncthreads();

    // ---- reduce pass 2 (cols 128..255)
    {
        int colp = tid & 63;
        int seg  = tid >> 6;
        int col2 = colp * 2;
        int base = seg * 16;
        float s0 = 0.f, s1 = 0.f;
#pragma unroll 4
        for (int i = 0; i < 16; ++i) {
            int gi = base + i;
            unsigned int u = *(const unsigned int*)&He[gi * 136 + col2];
            s0 += bf2f((unsigned short)u);
            s1 += bf2f((unsigned short)(u >> 16));
            if (i == 15 || ds[gi + 1] != ds[gi]) {
                float* dst = &s[(size_t)ds[gi] * 256 + 128 + col2];
                atomicAdd(dst, s0);
                atomicAdd(dst + 1, s1);
                s0 = 0.f; s1 = 0.f;
            }
        }
    }
}

// ---------------- node MLP (16 nodes/block -> 625 blocks) ----------------
__global__ __launch_bounds__(256, 2) void node_kernel(
    const float* __restrict__ x,
    const float* __restrict__ g,
    const float* __restrict__ s,
    const int* __restrict__ cnt,
    const unsigned short* __restrict__ wt0, const float* __restrict__ b0,
    const unsigned short* __restrict__ wt1, const float* __restrict__ b1,
    const unsigned short* __restrict__ wt2, const float* __restrict__ b2,
    const unsigned short* __restrict__ wt3, const float* __restrict__ b3,
    float* __restrict__ out)
{
    // Aliased LDS (17920 B):
    //   Abig [16][424] @0; HsA [16][136] @13568; HsB=@0 (Abig dead after pre-L1 barrier).
    __shared__ __align__(16) char NU[17920];
    unsigned short* Abig = (unsigned short*)NU;
    unsigned short* HsA  = (unsigned short*)(NU + 13568);
    unsigned short* HsB  = (unsigned short*)NU;

    const int tid = threadIdx.x;
    const int node0 = blockIdx.x * 16;   // grid 625 * 16 = 10000 exact

    // x part: cols 0..127 (16 rows x 32 float4 parts = 512 tasks)
#pragma unroll
    for (int i = 0; i < 2; ++i) {
        int task = tid + i * 256;
        int row = task >> 5, part = task & 31;
        float4 v = *(const float4*)(x + (size_t)(node0 + row) * 128 + part * 4);
        uint2 pk; pk.x = pk2(v.x, v.y); pk.y = pk2(v.z, v.w);
        *(uint2*)&Abig[row * 424 + part * 4] = pk;
    }
    // agg part: cols 128..383 (s / max(cnt,1)) (16 rows x 64 parts = 1024 tasks)
#pragma unroll
    for (int i = 0; i < 4; ++i) {
        int task = tid + i * 256;
        int row = task >> 6, part = task & 63;
        int node = node0 + row;
        float c = (float)cnt[node];
        float inv = 1.f / (c > 1.f ? c : 1.f);
        floatx4 v = *(const floatx4*)(s + (size_t)node * 256 + part * 4);
        uint2 pk;
        pk.x = pk2(v[0] * inv, v[1] * inv);
        pk.y = pk2(v[2] * inv, v[3] * inv);
        *(uint2*)&Abig[row * 424 + 128 + part * 4] = pk;
    }
    // global part: cols 384..415 (16 rows x 8 parts = 128 tasks)
    if (tid < 128) {
        int row = tid >> 3, part = tid & 7;
        float4 v = *(const float4*)(g + part * 4);
        uint2 pk; pk.x = pk2(v.x, v.y); pk.y = pk2(v.z, v.w);
        *(uint2*)&Abig[row * 424 + 384 + part * 4] = pk;
    }
    __syncthreads();

    const int lane = tid & 63;
    const int wave = tid >> 6;
    const int t32 = wave * 2;

    // L0 (K=416): streamed A. Prefetch L1 A-frags first.
    short8 a1[4][2];
    load_a<4, 2>(wt1, 8, t32, 0, lane, a1);
    __builtin_amdgcn_sched_barrier(0);
    {
        floatx4 acc[2][1];
        layer_stream<416, 128, 1>(Abig, 424, wt0, lane, wave * 32, acc);
        store_lds<2, 1>(acc, b0, lane, wave * 32, HsA, 136, true);
    }
    __syncthreads();

    short8 a2[4][2];
    load_a<4, 2>(wt2, 8, t32, 0, lane, a2);
    __builtin_amdgcn_sched_barrier(0);
    {
        floatx4 acc[2][1];
        // HsB (@0) overwrites Abig: safe — all Abig reads finished at the pre-L1 barrier.
        layer_mfma<128, 2, 1, true>(HsA, 136, lane, a1, acc);
        store_lds<2, 1>(acc, b1, lane, wave * 32, HsB, 136, true);
    }
    __syncthreads();

    short8 a3[4][2];
    load_a<4, 2>(wt3, 8, t32, 0, lane, a3);
    __builtin_amdgcn_sched_barrier(0);
    {
        floatx4 acc[2][1];
        layer_mfma<128, 2, 1, true>(HsB, 136, lane, a2, acc);
        store_lds<2, 1>(acc, b2, lane, wave * 32, HsA, 136, true);
    }
    __syncthreads();

    {
        floatx4 acc[2][1];
        layer_mfma<128, 2, 1, true>(HsA, 136, lane, a3, acc);
        const int quad = lane >> 4, mrow = lane & 15;
#pragma unroll
        for (int ft = 0; ft < 2; ++ft) {
            int fbase = wave * 32 + ft * 16 + quad * 4;
            float4 bv = *(const float4*)&b3[fbase];
            int node = node0 + mrow;
            float4 o;
            o.x = acc[ft][0][0] + bv.x;
            o.y = acc[ft][0][1] + bv.y;
            o.z = acc[ft][0][2] + bv.z;
            o.w = acc[ft][0][3] + bv.w;
            *(float4*)&out[(size_t)node * 128 + fbase] = o;  // fp32 vectorized
        }
    }
}

extern "C" void kernel_launch(void* const* d_in, const int* in_sizes, int n_in,
                              void* d_out, int out_size, void* d_ws, size_t ws_size,
                              hipStream_t stream)
{
    (void)in_sizes; (void)n_in; (void)out_size; (void)ws_size;

    const float* x  = (const float*)d_in[0];
    const int* eidx = (const int*)d_in[1];
    const float* ea = (const float*)d_in[2];
    const float* g  = (const float*)d_in[3];

    const float* w1[4]  = { (const float*)d_in[4],  (const float*)d_in[6],
                            (const float*)d_in[8],  (const float*)d_in[10] };
    const float* bb1[4] = { (const float*)d_in[5],  (const float*)d_in[7],
                            (const float*)d_in[9],  (const float*)d_in[11] };
    const float* w2[4]  = { (const float*)d_in[12], (const float*)d_in[14],
                            (const float*)d_in[16], (const float*)d_in[18] };
    const float* bb2[4] = { (const float*)d_in[13], (const float*)d_in[15],
                            (const float*)d_in[17], (const float*)d_in[19] };

    char* p = (char*)d_ws;
    unsigned short* wt1_0 = (unsigned short*)p; p += 256 * 128 * 2;
    unsigned short* wt1_1 = (unsigned short*)p; p += 128 * 128 * 2;
    unsigned short* wt1_2 = (unsigned short*)p; p += 128 * 128 * 2;
    unsigned short* wt1_3 = (unsigned short*)p; p += 128 * 256 * 2;
    unsigned short* wt2_0 = (unsigned short*)p; p += 416 * 128 * 2;
    unsigned short* wt2_1 = (unsigned short*)p; p += 128 * 128 * 2;
    unsigned short* wt2_2 = (unsigned short*)p; p += 128 * 128 * 2;
    unsigned short* wt2_3 = (unsigned short*)p; p += 128 * 128 * 2;
    float* s    = (float*)p; p += (size_t)N_NODES * 256 * 4;
    int* cnt    = (int*)p;   p += (size_t)N_NODES * 4;
    int* fill   = (int*)p;   p += (size_t)N_NODES * 4;
    int4* pack  = (int4*)p;  p += (size_t)E_EDGES * 16;

    // zero cnt only; s is zeroed by prep_kernel's third segment
    (void)hipMemsetAsync(cnt, 0, (size_t)N_NODES * 4, stream);

    TArgs ta;
    int bs = 0;
    auto set = [&](int i, const float* src, unsigned short* dst, int K, int Nn, int logN) {
        ta.d[i].src = src; ta.d[i].dst = dst; ta.d[i].nElem = K * Nn;
        ta.d[i].logN = logN; ta.d[i].blockStart = bs;
        bs += (K * Nn + 255) / 256;
    };
    set(0, w1[0], wt1_0, 256, 128, 7);
    set(1, w1[1], wt1_1, 128, 128, 7);
    set(2, w1[2], wt1_2, 128, 128, 7);
    set(3, w1[3], wt1_3, 128, 256, 8);
    set(4, w2[0], wt2_0, 416, 128, 7);
    set(5, w2[1], wt2_1, 128, 128, 7);
    set(6, w2[2], wt2_2, 128, 128, 7);
    set(7, w2[3], wt2_3, 128, 128, 7);

    int histBlocks = E_EDGES / 256;                       // 1250
    int zeroBlocks = (N_NODES * 256 / 4) / 256;           // 2500
    hipLaunchKernelGGL(prep_kernel, dim3(bs + histBlocks + zeroBlocks), dim3(256), 0, stream,
                       ta, eidx, cnt, (float4*)s, bs, bs + histBlocks);
    hipLaunchKernelGGL(scan_kernel, dim3(1), dim3(256), 0, stream, cnt, fill);
    hipLaunchKernelGGL(fill_kernel, dim3(E_EDGES / 256), dim3(256), 0, stream,
                       eidx, fill, pack);

    hipLaunchKernelGGL(edge_kernel, dim3(E_EDGES / 64), dim3(256), 0, stream,
                       x, ea, pack,
                       wt1_0, bb1[0], wt1_1, bb1[1], wt1_2, bb1[2], wt1_3, bb1[3],
                       s);

    hipLaunchKernelGGL(node_kernel, dim3(N_NODES / 16), dim3(256), 0, stream,
                       x, g, s, cnt,
                       wt2_0, bb2[0], wt2_1, bb2[1], wt2_2, bb2[2], wt2_3, bb2[3],
                       (float*)d_out);
}